// Round 4
// baseline (1394.577 us; speedup 1.0000x reference)
//
#include <hip/hip_runtime.h>
#include <hip/hip_fp16.h>
#include <hip/hip_cooperative_groups.h>
#include <math.h>

namespace cg = cooperative_groups;

#define NROWS 4194304
#define M4Q   (NROWS/4)          // 1048576 float4-groups
#define EPSV  1e-5f

#define BLK   512                // 2 blocks/CU on 256 CUs -> co-resident
#define THR   256
#define TOT   (BLK*THR)          // 131072 threads
#define GPT   (M4Q/TOT)          // 8 float4-groups per thread

#define SLOTS 32                 // stat partial slots (128 B apart)
#define SSTR  (SLOTS*32)         // floats per stage region
#define STATS_BYTES (9*SSTR*4)   // 36 KB

// Stage numbering: 0:x 1:h1 2:z1 3:h2 4:z2 5:h3 6:z3 7:h4 8:z4
// Stats: 20 floats/stage = 5 sums + 15 upper-tri second moments (exact, NROWS,
// computed on the fp16-rounded z values actually used downstream).
// Linear bias cancels inside BN (mean-subtracted): lins_b/lin9_b unused.
//
// R12 == R10 resubmit (broker timeouts x4, no data): single cooperative
// kernel, z resident in registers as fp16 (80 VGPR), grid.sync() between
// stat phases. Phase B reloads f1 from LDS (F1s persists) to keep the
// cross-sync live set low under the 256-VGPR cap that
// __launch_bounds__(256,2) co-residency needs.

struct __align__(8) h4 { __half2 lo, hi; };

__device__ __forceinline__ h4 f4_to_h4(const float4& f){
  h4 r; r.lo = __floats2half2_rn(f.x, f.y); r.hi = __floats2half2_rn(f.z, f.w);
  return r;
}
__device__ __forceinline__ float4 h4_to_f4(const h4& h){
  float2 a = __half22float2(h.lo), b = __half22float2(h.hi);
  return make_float4(a.x, a.y, b.x, b.y);
}

__device__ __forceinline__ float4 mk4(float v){ return make_float4(v,v,v,v); }
__device__ __forceinline__ float4 fma44(float a, const float4& b, const float4& c){
  return make_float4(fmaf(a,b.x,c.x), fmaf(a,b.y,c.y), fmaf(a,b.z,c.z), fmaf(a,b.w,c.w));
}
__device__ __forceinline__ float4 relu4(const float4& a){
  return make_float4(fmaxf(a.x,0.f),fmaxf(a.y,0.f),fmaxf(a.z,0.f),fmaxf(a.w,0.f));
}

__device__ __forceinline__ void acc_stats(const float4 z[5], float acc[20]){
  #pragma unroll
  for(int d=0; d<5; ++d) acc[d] += (z[d].x + z[d].y) + (z[d].z + z[d].w);
  int k = 5;
  #pragma unroll
  for(int d=0; d<5; ++d){
    #pragma unroll
    for(int e=d; e<5; ++e){
      acc[k] += z[d].x*z[e].x + z[d].y*z[e].y + z[d].z*z[e].z + z[d].w*z[e].w;
      ++k;
    }
  }
}

// Fold BN(Lin(z)) into affine y = A z + c from raw stats sums (scaled by invN).
__device__ __forceinline__ void fold_generic(const float* __restrict__ sums,
                                             const float* __restrict__ W,
                                             const float* __restrict__ g,
                                             const float* __restrict__ be,
                                             int c, float invN,
                                             float* Arow, float* cout){
  float mu[5];
  #pragma unroll
  for(int d=0;d<5;++d) mu[d] = sums[d]*invN;
  float wr[5];
  #pragma unroll
  for(int d=0;d<5;++d) wr[d] = W[c*5+d];
  float m = 0.f, v = 0.f;
  #pragma unroll
  for(int d=0;d<5;++d){
    m += wr[d]*mu[d];
    #pragma unroll
    for(int e=0;e<5;++e){
      const int dd = d<e?d:e, ee = d<e?e:d;
      const float cov = sums[5 + dd*5+ee - (dd*(dd+1))/2]*invN - mu[d]*mu[e];
      v += wr[d]*wr[e]*cov;
    }
  }
  const float s = g[c] / sqrtf(v + EPSV);
  #pragma unroll
  for(int d=0;d<5;++d) Arow[d] = s*wr[d];
  *cout = be[c] - s*m;
}

// Block-reduce acc[20]; atomicAdd into this block's slot (slots 128 B apart).
__device__ __forceinline__ void reduce_slots(float acc[20], float* stage){
  #pragma unroll
  for(int k=0;k<20;++k){
    float v = acc[k];
    #pragma unroll
    for(int m=32;m>=1;m>>=1) v += __shfl_xor(v, m);
    acc[k] = v;
  }
  __shared__ float red[(THR/64)*20];
  const int lane = threadIdx.x & 63, wv = threadIdx.x >> 6;
  if(lane==0){
    #pragma unroll
    for(int k=0;k<20;++k) red[wv*20+k] = acc[k];
  }
  __syncthreads();
  if(threadIdx.x < 20){
    float s = 0.f;
    #pragma unroll
    for(int w=0; w<THR/64; ++w) s += red[w*20 + threadIdx.x];
    atomicAdd(stage + (blockIdx.x & (SLOTS-1))*32 + threadIdx.x, s);
  }
}

// Gather the 32 slot partials of a stage into raw[20] (LDS).
// Agent-scope atomic loads: values come from other blocks' atomicAdds across
// XCDs; grid.sync orders them, the agent-scope load guarantees no stale L1.
__device__ __forceinline__ void sum_slots_coherent(const float* __restrict__ stage,
                                                   float* raw){
  if(threadIdx.x < 20){
    float s = 0.f;
    #pragma unroll
    for(int j=0;j<SLOTS;++j)
      s += __hip_atomic_load(stage + j*32 + (int)threadIdx.x,
                             __ATOMIC_RELAXED, __HIP_MEMORY_SCOPE_AGENT);
    raw[threadIdx.x] = s;
  }
  __syncthreads();
}

// ---- fused cooperative kernel: whole network, z resident in registers ----
__global__ __launch_bounds__(THR, 2)
void k_fused(const float* __restrict__ x, float* __restrict__ stats,
             const float* __restrict__ lins_w, const float* __restrict__ bn_g,
             const float* __restrict__ bn_b, const float* __restrict__ skips_w,
             const float* __restrict__ skips_b, const float* __restrict__ lin9_w,
             const float* __restrict__ bn9_g, const float* __restrict__ bn9_b,
             const float* __restrict__ lin10_w, const float* __restrict__ lin10_b,
             float* __restrict__ out){
  cg::grid_group grid = cg::this_grid();
  const int tid = blockIdx.x*THR + threadIdx.x;

  __shared__ float raw[20], rawB[20];
  __shared__ float F1s[30], F2s[30], SWs[25], A9c[12];

  h4 zh[GPT][5];                 // fp16 z, resident across all stages
  float acc[20];
  #pragma unroll
  for(int k=0;k<20;++k) acc[k]=0.f;

  // ---- stage 0: read x (AoS f32), transpose, round to fp16, stats ----
  #pragma unroll
  for(int g=0; g<GPT; ++g){
    const int G = tid + g*TOT;
    union { float4 v[5]; float f[20]; } u;
    const float4* xp = (const float4*)x + (size_t)G*5;
    #pragma unroll
    for(int q=0;q<5;++q) u.v[q] = xp[q];
    float4 z[5];
    #pragma unroll
    for(int c=0;c<5;++c) z[c] = make_float4(u.f[c], u.f[5+c], u.f[10+c], u.f[15+c]);
    #pragma unroll
    for(int c=0;c<5;++c){
      h4 hz = f4_to_h4(z[c]);
      zh[g][c] = hz;
      z[c] = h4_to_f4(hz);       // stats on the rounded values (consistency)
    }
    acc_stats(z, acc);
  }
  reduce_slots(acc, stats + 0*SSTR);
  grid.sync();

  #pragma unroll 1
  for(int b=0;b<4;++b){
    const int i = 2*b, j = i+1;

    // ---- phase A: fold F1, stats of h = relu(F1 z) ----
    sum_slots_coherent(stats + i*SSTR, raw);
    if(threadIdx.x < 5)
      fold_generic(raw, lins_w+25*i, bn_g+5*i, bn_b+5*i, (int)threadIdx.x,
                   1.0f/(float)NROWS, &F1s[threadIdx.x*5], &F1s[25+threadIdx.x]);
    __syncthreads();
    {
      float f1[30];
      #pragma unroll
      for(int k=0;k<30;++k) f1[k] = F1s[k];
      #pragma unroll
      for(int k=0;k<20;++k) acc[k]=0.f;
      #pragma unroll
      for(int g=0; g<GPT; ++g){
        float4 z[5], h[5];
        #pragma unroll
        for(int c=0;c<5;++c) z[c] = h4_to_f4(zh[g][c]);
        #pragma unroll
        for(int c=0;c<5;++c){
          float4 u = mk4(f1[25+c]);
          #pragma unroll
          for(int d=0;d<5;++d) u = fma44(f1[c*5+d], z[d], u);
          h[c] = relu4(u);
        }
        acc_stats(h, acc);
      }
    }
    reduce_slots(acc, stats + j*SSTR);
    grid.sync();

    // ---- phase B: fold F2+skip, z' = relu(F2 relu(F1 z) + SW z + c') ----
    // F1s persists in LDS across grid.sync: reload f1 here instead of keeping
    // a 30-VGPR live range through phase A.
    sum_slots_coherent(stats + j*SSTR, rawB);
    if(threadIdx.x < 5){
      fold_generic(rawB, lins_w+25*j, bn_g+5*j, bn_b+5*j, (int)threadIdx.x,
                   1.0f/(float)NROWS, &F2s[threadIdx.x*5], &F2s[25+threadIdx.x]);
      F2s[25+threadIdx.x] += skips_b[5*b + threadIdx.x];   // merge skip bias
    }
    if(threadIdx.x >= 64 && threadIdx.x < 89)
      SWs[threadIdx.x-64] = skips_w[25*b + (threadIdx.x-64)];
    __syncthreads();
    {
      float f1[30], f2[30], sw[25];
      #pragma unroll
      for(int k=0;k<30;++k){ f1[k] = F1s[k]; f2[k] = F2s[k]; }
      #pragma unroll
      for(int k=0;k<25;++k) sw[k] = SWs[k];
      #pragma unroll
      for(int k=0;k<20;++k) acc[k]=0.f;
      #pragma unroll
      for(int g=0; g<GPT; ++g){
        float4 z[5], h[5], t[5];
        #pragma unroll
        for(int c=0;c<5;++c) z[c] = h4_to_f4(zh[g][c]);
        #pragma unroll
        for(int c=0;c<5;++c){
          float4 u = mk4(f1[25+c]);
          #pragma unroll
          for(int d=0;d<5;++d) u = fma44(f1[c*5+d], z[d], u);
          h[c] = relu4(u);
        }
        #pragma unroll
        for(int c=0;c<5;++c){
          float4 u = mk4(f2[25+c]);
          #pragma unroll
          for(int d=0;d<5;++d){
            u = fma44(f2[c*5+d], h[d], u);
            u = fma44(sw[c*5+d], z[d], u);
          }
          h4 hz = f4_to_h4(relu4(u));
          zh[g][c] = hz;
          t[c] = h4_to_f4(hz);   // stats on the rounded values
        }
        acc_stats(t, acc);
      }
    }
    reduce_slots(acc, stats + (i+2)*SSTR);
    grid.sync();
  }

  // ---- final: fold lin9+bn9, apply lin10, write out (f32) ----
  sum_slots_coherent(stats + 8*SSTR, raw);
  if(threadIdx.x < 2)
    fold_generic(raw, lin9_w, bn9_g, bn9_b, (int)threadIdx.x,
                 1.0f/(float)NROWS, &A9c[threadIdx.x*5], &A9c[10+threadIdx.x]);
  __syncthreads();
  float f9[12];
  #pragma unroll
  for(int k=0;k<12;++k) f9[k] = A9c[k];
  const float w10a = lin10_w[0], w10b = lin10_w[1], b10 = lin10_b[0];
  #pragma unroll
  for(int g=0; g<GPT; ++g){
    const int G = tid + g*TOT;
    float4 z[5];
    #pragma unroll
    for(int c=0;c<5;++c) z[c] = h4_to_f4(zh[g][c]);
    float4 u0 = mk4(f9[10]), u1 = mk4(f9[11]);
    #pragma unroll
    for(int d=0;d<5;++d){ u0 = fma44(f9[d], z[d], u0); u1 = fma44(f9[5+d], z[d], u1); }
    u0 = relu4(u0); u1 = relu4(u1);
    float4 o = mk4(b10);
    o = fma44(w10a, u0, o);
    o = fma44(w10b, u1, o);
    ((float4*)out)[G] = o;
  }
}

// ---- fallback (non-cooperative): exact full-data recompute-from-x chain, f32 ----
__global__ __launch_bounds__(THR)
void k_fromx(const float* __restrict__ x, float* __restrict__ stats,
             const float* __restrict__ lins_w, const float* __restrict__ bn_g,
             const float* __restrict__ bn_b, const float* __restrict__ skips_w,
             const float* __restrict__ skips_b, const float* __restrict__ lin9_w,
             const float* __restrict__ bn9_g, const float* __restrict__ bn9_b,
             const float* __restrict__ lin10_w, const float* __restrict__ lin10_b,
             float* __restrict__ out, int target, int do_final){
  __shared__ float rawAll[9][20];
  __shared__ float FA[8][30];
  __shared__ float SW[100];
  __shared__ float A9c[12];
  const int tix = threadIdx.x;
  const int nf = do_final ? 9 : target;
  if(tix < 20*nf){
    const int L = tix/20, k = tix%20;
    float s = 0.f;
    #pragma unroll
    for(int j=0;j<SLOTS;++j) s += stats[L*SSTR + j*32 + k];
    rawAll[L][k] = s;
  }
  __syncthreads();
  const int nlay = do_final ? 8 : (target < 8 ? target : 8);
  if(tix < 5*nlay){
    const int L = tix/5, c = tix%5;
    fold_generic(&rawAll[L][0], lins_w+25*L, bn_g+5*L, bn_b+5*L, c,
                 1.0f/(float)NROWS, &FA[L][c*5], &FA[L][25+c]);
    if(L & 1) FA[L][25+c] += skips_b[(L>>1)*5 + c];
  } else if(tix >= 64 && tix < 164){
    SW[tix-64] = skips_w[tix-64];
  }
  if(do_final && tix >= 40 && tix < 42){
    const int c = tix-40;
    fold_generic(&rawAll[8][0], lin9_w, bn9_g, bn9_b, c,
                 1.0f/(float)NROWS, &A9c[c*5], &A9c[10+c]);
  }
  __syncthreads();
  float w10a=0.f, w10b=0.f, b10=0.f;
  if(do_final){ w10a = lin10_w[0]; w10b = lin10_w[1]; b10 = lin10_b[0]; }
  float acc[20];
  #pragma unroll
  for(int k=0;k<20;++k) acc[k]=0.f;
  const int gid = blockIdx.x*THR + tix;
  const int steps = do_final ? 8 : target;
  for(int t0=gid; t0<M4Q; t0+=TOT){
    union { float4 v[5]; float f[20]; } u;
    const float4* xp = (const float4*)x + (size_t)t0*5;
    #pragma unroll
    for(int q=0;q<5;++q) u.v[q] = xp[q];
    float4 z[5], h[5];
    #pragma unroll
    for(int c=0;c<5;++c) z[c] = make_float4(u.f[c], u.f[5+c], u.f[10+c], u.f[15+c]);
    #pragma unroll 1
    for(int s=1; s<=steps; ++s){
      const int L = s-1, b = L>>1;
      if(s & 1){
        #pragma unroll
        for(int c=0;c<5;++c){
          float4 t2 = mk4(FA[L][25+c]);
          #pragma unroll
          for(int d=0;d<5;++d) t2 = fma44(FA[L][c*5+d], z[d], t2);
          h[c] = relu4(t2);
        }
      } else {
        float4 zn[5];
        #pragma unroll
        for(int c=0;c<5;++c){
          float4 t2 = mk4(FA[L][25+c]);
          #pragma unroll
          for(int d=0;d<5;++d){
            t2 = fma44(FA[L][c*5+d], h[d], t2);
            t2 = fma44(SW[b*25+c*5+d], z[d], t2);
          }
          zn[c] = relu4(t2);
        }
        #pragma unroll
        for(int c=0;c<5;++c) z[c] = zn[c];
      }
    }
    if(do_final){
      float4 u0 = mk4(A9c[10]), u1 = mk4(A9c[11]);
      #pragma unroll
      for(int d=0;d<5;++d){ u0 = fma44(A9c[d], z[d], u0); u1 = fma44(A9c[5+d], z[d], u1); }
      u0 = relu4(u0); u1 = relu4(u1);
      float4 o = mk4(b10);
      o = fma44(w10a, u0, o);
      o = fma44(w10b, u1, o);
      ((float4*)out)[t0] = o;
    } else {
      if(steps & 1) acc_stats(h, acc);
      else          acc_stats(z, acc);
    }
  }
  if(!do_final) reduce_slots(acc, stats + target*SSTR);
}

extern "C" void kernel_launch(void* const* d_in, const int* in_sizes, int n_in,
                              void* d_out, int out_size, void* d_ws, size_t ws_size,
                              hipStream_t stream){
  (void)in_sizes; (void)n_in; (void)out_size;
  const float* x       = (const float*)d_in[0];
  const float* lins_w  = (const float*)d_in[1];
  // d_in[2] = lins_b: cancels inside BN, unused
  const float* skips_w = (const float*)d_in[3];
  const float* skips_b = (const float*)d_in[4];
  const float* bn_g    = (const float*)d_in[5];
  const float* bn_b    = (const float*)d_in[6];
  const float* lin9_w  = (const float*)d_in[7];
  // d_in[8] = lin9_b: cancels inside BN, unused
  const float* bn9_g   = (const float*)d_in[9];
  const float* bn9_b   = (const float*)d_in[10];
  const float* lin10_w = (const float*)d_in[11];
  const float* lin10_b = (const float*)d_in[12];
  float* out = (float*)d_out;

  float* stats = (float*)d_ws;
  hipMemsetAsync(stats, 0, STATS_BYTES, stream);

  void* args[13] = {
    (void*)&x, (void*)&stats, (void*)&lins_w, (void*)&bn_g, (void*)&bn_b,
    (void*)&skips_w, (void*)&skips_b, (void*)&lin9_w, (void*)&bn9_g,
    (void*)&bn9_b, (void*)&lin10_w, (void*)&lin10_b, (void*)&out
  };
  hipError_t e = hipLaunchCooperativeKernel((const void*)k_fused,
                                            dim3(BLK), dim3(THR),
                                            args, 0, stream);
  if(e != hipSuccess){
    // non-cooperative fallback: exact recompute-from-x chain (stats-only ws)
    for(int s=0; s<=8; ++s)
      k_fromx<<<BLK, THR, 0, stream>>>(x, stats, lins_w, bn_g, bn_b, skips_w,
                                       skips_b, lin9_w, bn9_g, bn9_b, lin10_w,
                                       lin10_b, out, s, 0);
    k_fromx<<<BLK, THR, 0, stream>>>(x, stats, lins_w, bn_g, bn_b, skips_w,
                                     skips_b, lin9_w, bn9_g, bn9_b, lin10_w,
                                     lin10_b, out, 8, 1);
  }
}

// Round 6
// 602.342 us; speedup vs baseline: 2.3153x; 2.3153x over previous
//
#include <hip/hip_runtime.h>
#include <hip/hip_fp16.h>
#include <hip/hip_cooperative_groups.h>
#include <math.h>

namespace cg = cooperative_groups;

#define NROWS 4194304
#define M4Q   (NROWS/4)          // 1048576 float4-groups
#define EPSV  1e-5f

#define BLK   512                // 2 blocks/CU on 256 CUs -> co-resident
#define THR   256
#define TOT   (BLK*THR)          // 131072 threads
#define GPT   (M4Q/TOT)          // 8 float4-groups per thread
#define GLDS  6                  // groups kept in LDS
#define GREG  (GPT-GLDS)         // 2 groups kept in VGPRs (static-indexed)

#define SLOTS 32                 // stat partial slots (128 B apart)
#define SSTR  (SLOTS*32)         // floats per stage region
#define STATS_BYTES (9*SSTR*4)   // 36 KB

// Stage numbering: 0:x 1:h1 2:z1 3:h2 4:z2 5:h3 6:z3 7:h4 8:z4
// Stats: 20 floats/stage = 5 sums + 15 upper-tri second moments (exact, NROWS,
// computed on the fp16-rounded z values actually used downstream).
// Linear bias cancels inside BN (mean-subtracted): lins_b/lin9_b unused.
//
// R14 == R13 resubmit (broker timeout, no data). R12 measured 1265us —
// VGPR_Count=128 (allocator targeted 4 waves/EU) => zh+acc spilled to
// scratch: WRITE 1.5GB / FETCH 0.93GB matches the spill ledger. Fix:
// (a) 6 of 8 z-groups in LDS (uint2 zlds[30][256], lane-contiguous,
// 61.4KB/block; 2 blocks/CU = 125KB <= 160KB), 2 groups in regs;
// (b) amdgpu_waves_per_eu(2,2) pins the 256-VGPR budget;
// (c) group loops unroll-2 (not full) to bound scheduler live sets.

struct __align__(8) h4 { __half2 lo, hi; };   // kept for k_fromx compat

__device__ __forceinline__ uint2 pack4(const float4 f){
  union{ __half2 h; unsigned u; } a, b;
  a.h = __floats2half2_rn(f.x, f.y);
  b.h = __floats2half2_rn(f.z, f.w);
  return make_uint2(a.u, b.u);
}
__device__ __forceinline__ float4 unpack4(const uint2 p){
  union{ unsigned u; __half2 h; } a, b;
  a.u = p.x; b.u = p.y;
  float2 lo = __half22float2(a.h), hi = __half22float2(b.h);
  return make_float4(lo.x, lo.y, hi.x, hi.y);
}

__device__ __forceinline__ float4 mk4(float v){ return make_float4(v,v,v,v); }
__device__ __forceinline__ float4 fma44(float a, const float4& b, const float4& c){
  return make_float4(fmaf(a,b.x,c.x), fmaf(a,b.y,c.y), fmaf(a,b.z,c.z), fmaf(a,b.w,c.w));
}
__device__ __forceinline__ float4 relu4(const float4& a){
  return make_float4(fmaxf(a.x,0.f),fmaxf(a.y,0.f),fmaxf(a.z,0.f),fmaxf(a.w,0.f));
}

__device__ __forceinline__ void acc_stats(const float4 z[5], float acc[20]){
  #pragma unroll
  for(int d=0; d<5; ++d) acc[d] += (z[d].x + z[d].y) + (z[d].z + z[d].w);
  int k = 5;
  #pragma unroll
  for(int d=0; d<5; ++d){
    #pragma unroll
    for(int e=d; e<5; ++e){
      acc[k] += z[d].x*z[e].x + z[d].y*z[e].y + z[d].z*z[e].z + z[d].w*z[e].w;
      ++k;
    }
  }
}

// h = relu(F1 z + c1)
__device__ __forceinline__ void bodyH(const float4 z[5], const float* __restrict__ f1,
                                      float4 h[5]){
  #pragma unroll
  for(int c=0;c<5;++c){
    float4 u = mk4(f1[25+c]);
    #pragma unroll
    for(int d=0;d<5;++d) u = fma44(f1[c*5+d], z[d], u);
    h[c] = relu4(u);
  }
}

// t = fp16(relu(F2 h + SW z + c2)); packed out + rounded float4 out
__device__ __forceinline__ void bodyB(const float4 z[5], const float4 h[5],
                                      const float* __restrict__ f2,
                                      const float* __restrict__ sw,
                                      uint2 pz[5], float4 t[5]){
  #pragma unroll
  for(int c=0;c<5;++c){
    float4 u = mk4(f2[25+c]);
    #pragma unroll
    for(int d=0;d<5;++d){
      u = fma44(f2[c*5+d], h[d], u);
      u = fma44(sw[c*5+d], z[d], u);
    }
    uint2 p = pack4(relu4(u));
    pz[c] = p;
    t[c] = unpack4(p);
  }
}

// Fold BN(Lin(z)) into affine y = A z + c from raw stats sums (scaled by invN).
__device__ __forceinline__ void fold_generic(const float* __restrict__ sums,
                                             const float* __restrict__ W,
                                             const float* __restrict__ g,
                                             const float* __restrict__ be,
                                             int c, float invN,
                                             float* Arow, float* cout){
  float mu[5];
  #pragma unroll
  for(int d=0;d<5;++d) mu[d] = sums[d]*invN;
  float wr[5];
  #pragma unroll
  for(int d=0;d<5;++d) wr[d] = W[c*5+d];
  float m = 0.f, v = 0.f;
  #pragma unroll
  for(int d=0;d<5;++d){
    m += wr[d]*mu[d];
    #pragma unroll
    for(int e=0;e<5;++e){
      const int dd = d<e?d:e, ee = d<e?e:d;
      const float cov = sums[5 + dd*5+ee - (dd*(dd+1))/2]*invN - mu[d]*mu[e];
      v += wr[d]*wr[e]*cov;
    }
  }
  const float s = g[c] / sqrtf(v + EPSV);
  #pragma unroll
  for(int d=0;d<5;++d) Arow[d] = s*wr[d];
  *cout = be[c] - s*m;
}

// Block-reduce acc[20]; atomicAdd into this block's slot (slots 128 B apart).
__device__ __forceinline__ void reduce_slots(float acc[20], float* stage){
  #pragma unroll
  for(int k=0;k<20;++k){
    float v = acc[k];
    #pragma unroll
    for(int m=32;m>=1;m>>=1) v += __shfl_xor(v, m);
    acc[k] = v;
  }
  __shared__ float red[(THR/64)*20];
  const int lane = threadIdx.x & 63, wv = threadIdx.x >> 6;
  if(lane==0){
    #pragma unroll
    for(int k=0;k<20;++k) red[wv*20+k] = acc[k];
  }
  __syncthreads();
  if(threadIdx.x < 20){
    float s = 0.f;
    #pragma unroll
    for(int w=0; w<THR/64; ++w) s += red[w*20 + threadIdx.x];
    atomicAdd(stage + (blockIdx.x & (SLOTS-1))*32 + threadIdx.x, s);
  }
}

// Gather the 32 slot partials of a stage into raw[20] (LDS).
__device__ __forceinline__ void sum_slots_coherent(const float* __restrict__ stage,
                                                   float* raw){
  if(threadIdx.x < 20){
    float s = 0.f;
    #pragma unroll
    for(int j=0;j<SLOTS;++j)
      s += __hip_atomic_load(stage + j*32 + (int)threadIdx.x,
                             __ATOMIC_RELAXED, __HIP_MEMORY_SCOPE_AGENT);
    raw[threadIdx.x] = s;
  }
  __syncthreads();
}

// ---- fused cooperative kernel: whole network, z in LDS(6)+regs(2) ----
__global__ __attribute__((amdgpu_flat_work_group_size(THR,THR)))
           __attribute__((amdgpu_waves_per_eu(2,2)))
void k_fused(const float* __restrict__ x, float* __restrict__ stats,
             const float* __restrict__ lins_w, const float* __restrict__ bn_g,
             const float* __restrict__ bn_b, const float* __restrict__ skips_w,
             const float* __restrict__ skips_b, const float* __restrict__ lin9_w,
             const float* __restrict__ bn9_g, const float* __restrict__ bn9_b,
             const float* __restrict__ lin10_w, const float* __restrict__ lin10_b,
             float* __restrict__ out){
  cg::grid_group grid = cg::this_grid();
  const int tx  = threadIdx.x;
  const int tid = blockIdx.x*THR + tx;

  __shared__ uint2 zlds[GLDS*5][THR];   // 61440 B, lane-contiguous (no conflicts)
  __shared__ float raw[20], rawB[20];
  __shared__ float F1s[30], F2s[30], SWs[25], A9c[12];

  uint2 zreg[GREG][5];                  // 20 VGPRs, static-indexed only
  float acc[20];
  #pragma unroll
  for(int k=0;k<20;++k) acc[k]=0.f;

  // ---- stage 0: read x (AoS f32), transpose, round to fp16, stats ----
  #pragma unroll 2
  for(int g=0; g<GLDS; ++g){
    const int G = tid + g*TOT;
    union { float4 v[5]; float f[20]; } u;
    const float4* xp = (const float4*)x + (size_t)G*5;
    #pragma unroll
    for(int q=0;q<5;++q) u.v[q] = xp[q];
    float4 z[5];
    #pragma unroll
    for(int c=0;c<5;++c){
      uint2 p = pack4(make_float4(u.f[c], u.f[5+c], u.f[10+c], u.f[15+c]));
      zlds[g*5+c][tx] = p;
      z[c] = unpack4(p);               // stats on the rounded values
    }
    acc_stats(z, acc);
  }
  #pragma unroll
  for(int gr=0; gr<GREG; ++gr){
    const int G = tid + (GLDS+gr)*TOT;
    union { float4 v[5]; float f[20]; } u;
    const float4* xp = (const float4*)x + (size_t)G*5;
    #pragma unroll
    for(int q=0;q<5;++q) u.v[q] = xp[q];
    float4 z[5];
    #pragma unroll
    for(int c=0;c<5;++c){
      uint2 p = pack4(make_float4(u.f[c], u.f[5+c], u.f[10+c], u.f[15+c]));
      zreg[gr][c] = p;
      z[c] = unpack4(p);
    }
    acc_stats(z, acc);
  }
  reduce_slots(acc, stats + 0*SSTR);
  grid.sync();

  #pragma unroll 1
  for(int b=0;b<4;++b){
    const int i = 2*b, j = i+1;

    // ---- phase A: fold F1, stats of h = relu(F1 z) ----
    sum_slots_coherent(stats + i*SSTR, raw);
    if(tx < 5)
      fold_generic(raw, lins_w+25*i, bn_g+5*i, bn_b+5*i, tx,
                   1.0f/(float)NROWS, &F1s[tx*5], &F1s[25+tx]);
    __syncthreads();
    {
      float f1[30];
      #pragma unroll
      for(int k=0;k<30;++k) f1[k] = F1s[k];
      #pragma unroll
      for(int k=0;k<20;++k) acc[k]=0.f;
      #pragma unroll 2
      for(int g=0; g<GLDS; ++g){
        float4 z[5], h[5];
        #pragma unroll
        for(int c=0;c<5;++c) z[c] = unpack4(zlds[g*5+c][tx]);
        bodyH(z, f1, h);
        acc_stats(h, acc);
      }
      #pragma unroll
      for(int gr=0; gr<GREG; ++gr){
        float4 z[5], h[5];
        #pragma unroll
        for(int c=0;c<5;++c) z[c] = unpack4(zreg[gr][c]);
        bodyH(z, f1, h);
        acc_stats(h, acc);
      }
    }
    reduce_slots(acc, stats + j*SSTR);
    grid.sync();

    // ---- phase B: fold F2+skip, z' = relu(F2 relu(F1 z) + SW z + c') ----
    sum_slots_coherent(stats + j*SSTR, rawB);
    if(tx < 5){
      fold_generic(rawB, lins_w+25*j, bn_g+5*j, bn_b+5*j, tx,
                   1.0f/(float)NROWS, &F2s[tx*5], &F2s[25+tx]);
      F2s[25+tx] += skips_b[5*b + tx];   // merge skip bias
    }
    if(tx >= 64 && tx < 89)
      SWs[tx-64] = skips_w[25*b + (tx-64)];
    __syncthreads();
    {
      float f1[30], f2[30], sw[25];
      #pragma unroll
      for(int k=0;k<30;++k){ f1[k] = F1s[k]; f2[k] = F2s[k]; }
      #pragma unroll
      for(int k=0;k<25;++k) sw[k] = SWs[k];
      #pragma unroll
      for(int k=0;k<20;++k) acc[k]=0.f;
      #pragma unroll 2
      for(int g=0; g<GLDS; ++g){
        float4 z[5], h[5], t[5];
        uint2 pz[5];
        #pragma unroll
        for(int c=0;c<5;++c) z[c] = unpack4(zlds[g*5+c][tx]);
        bodyH(z, f1, h);
        bodyB(z, h, f2, sw, pz, t);
        #pragma unroll
        for(int c=0;c<5;++c) zlds[g*5+c][tx] = pz[c];
        acc_stats(t, acc);
      }
      #pragma unroll
      for(int gr=0; gr<GREG; ++gr){
        float4 z[5], h[5], t[5];
        uint2 pz[5];
        #pragma unroll
        for(int c=0;c<5;++c) z[c] = unpack4(zreg[gr][c]);
        bodyH(z, f1, h);
        bodyB(z, h, f2, sw, pz, t);
        #pragma unroll
        for(int c=0;c<5;++c) zreg[gr][c] = pz[c];
        acc_stats(t, acc);
      }
    }
    reduce_slots(acc, stats + (i+2)*SSTR);
    grid.sync();
  }

  // ---- final: fold lin9+bn9, apply lin10, write out (f32) ----
  sum_slots_coherent(stats + 8*SSTR, raw);
  if(tx < 2)
    fold_generic(raw, lin9_w, bn9_g, bn9_b, tx,
                 1.0f/(float)NROWS, &A9c[tx*5], &A9c[10+tx]);
  __syncthreads();
  float f9[12];
  #pragma unroll
  for(int k=0;k<12;++k) f9[k] = A9c[k];
  const float w10a = lin10_w[0], w10b = lin10_w[1], b10 = lin10_b[0];
  #pragma unroll 2
  for(int g=0; g<GLDS; ++g){
    const int G = tid + g*TOT;
    float4 z[5];
    #pragma unroll
    for(int c=0;c<5;++c) z[c] = unpack4(zlds[g*5+c][tx]);
    float4 u0 = mk4(f9[10]), u1 = mk4(f9[11]);
    #pragma unroll
    for(int d=0;d<5;++d){ u0 = fma44(f9[d], z[d], u0); u1 = fma44(f9[5+d], z[d], u1); }
    u0 = relu4(u0); u1 = relu4(u1);
    float4 o = mk4(b10);
    o = fma44(w10a, u0, o);
    o = fma44(w10b, u1, o);
    ((float4*)out)[G] = o;
  }
  #pragma unroll
  for(int gr=0; gr<GREG; ++gr){
    const int G = tid + (GLDS+gr)*TOT;
    float4 z[5];
    #pragma unroll
    for(int c=0;c<5;++c) z[c] = unpack4(zreg[gr][c]);
    float4 u0 = mk4(f9[10]), u1 = mk4(f9[11]);
    #pragma unroll
    for(int d=0;d<5;++d){ u0 = fma44(f9[d], z[d], u0); u1 = fma44(f9[5+d], z[d], u1); }
    u0 = relu4(u0); u1 = relu4(u1);
    float4 o = mk4(b10);
    o = fma44(w10a, u0, o);
    o = fma44(w10b, u1, o);
    ((float4*)out)[G] = o;
  }
}

// ---- fallback (non-cooperative): exact full-data recompute-from-x chain, f32 ----
__global__ __launch_bounds__(THR)
void k_fromx(const float* __restrict__ x, float* __restrict__ stats,
             const float* __restrict__ lins_w, const float* __restrict__ bn_g,
             const float* __restrict__ bn_b, const float* __restrict__ skips_w,
             const float* __restrict__ skips_b, const float* __restrict__ lin9_w,
             const float* __restrict__ bn9_g, const float* __restrict__ bn9_b,
             const float* __restrict__ lin10_w, const float* __restrict__ lin10_b,
             float* __restrict__ out, int target, int do_final){
  __shared__ float rawAll[9][20];
  __shared__ float FA[8][30];
  __shared__ float SW[100];
  __shared__ float A9c[12];
  const int tix = threadIdx.x;
  const int nf = do_final ? 9 : target;
  if(tix < 20*nf){
    const int L = tix/20, k = tix%20;
    float s = 0.f;
    #pragma unroll
    for(int j=0;j<SLOTS;++j) s += stats[L*SSTR + j*32 + k];
    rawAll[L][k] = s;
  }
  __syncthreads();
  const int nlay = do_final ? 8 : (target < 8 ? target : 8);
  if(tix < 5*nlay){
    const int L = tix/5, c = tix%5;
    fold_generic(&rawAll[L][0], lins_w+25*L, bn_g+5*L, bn_b+5*L, c,
                 1.0f/(float)NROWS, &FA[L][c*5], &FA[L][25+c]);
    if(L & 1) FA[L][25+c] += skips_b[(L>>1)*5 + c];
  } else if(tix >= 64 && tix < 164){
    SW[tix-64] = skips_w[tix-64];
  }
  if(do_final && tix >= 40 && tix < 42){
    const int c = tix-40;
    fold_generic(&rawAll[8][0], lin9_w, bn9_g, bn9_b, c,
                 1.0f/(float)NROWS, &A9c[c*5], &A9c[10+c]);
  }
  __syncthreads();
  float w10a=0.f, w10b=0.f, b10=0.f;
  if(do_final){ w10a = lin10_w[0]; w10b = lin10_w[1]; b10 = lin10_b[0]; }
  float acc[20];
  #pragma unroll
  for(int k=0;k<20;++k) acc[k]=0.f;
  const int gid = blockIdx.x*THR + tix;
  const int steps = do_final ? 8 : target;
  for(int t0=gid; t0<M4Q; t0+=TOT){
    union { float4 v[5]; float f[20]; } u;
    const float4* xp = (const float4*)x + (size_t)t0*5;
    #pragma unroll
    for(int q=0;q<5;++q) u.v[q] = xp[q];
    float4 z[5], h[5];
    #pragma unroll
    for(int c=0;c<5;++c) z[c] = make_float4(u.f[c], u.f[5+c], u.f[10+c], u.f[15+c]);
    #pragma unroll 1
    for(int s=1; s<=steps; ++s){
      const int L = s-1, b = L>>1;
      if(s & 1){
        #pragma unroll
        for(int c=0;c<5;++c){
          float4 t2 = mk4(FA[L][25+c]);
          #pragma unroll
          for(int d=0;d<5;++d) t2 = fma44(FA[L][c*5+d], z[d], t2);
          h[c] = relu4(t2);
        }
      } else {
        float4 zn[5];
        #pragma unroll
        for(int c=0;c<5;++c){
          float4 t2 = mk4(FA[L][25+c]);
          #pragma unroll
          for(int d=0;d<5;++d){
            t2 = fma44(FA[L][c*5+d], h[d], t2);
            t2 = fma44(SW[b*25+c*5+d], z[d], t2);
          }
          zn[c] = relu4(t2);
        }
        #pragma unroll
        for(int c=0;c<5;++c) z[c] = zn[c];
      }
    }
    if(do_final){
      float4 u0 = mk4(A9c[10]), u1 = mk4(A9c[11]);
      #pragma unroll
      for(int d=0;d<5;++d){ u0 = fma44(A9c[d], z[d], u0); u1 = fma44(A9c[5+d], z[d], u1); }
      u0 = relu4(u0); u1 = relu4(u1);
      float4 o = mk4(b10);
      o = fma44(w10a, u0, o);
      o = fma44(w10b, u1, o);
      ((float4*)out)[t0] = o;
    } else {
      if(steps & 1) acc_stats(h, acc);
      else          acc_stats(z, acc);
    }
  }
  if(!do_final) reduce_slots(acc, stats + target*SSTR);
}

extern "C" void kernel_launch(void* const* d_in, const int* in_sizes, int n_in,
                              void* d_out, int out_size, void* d_ws, size_t ws_size,
                              hipStream_t stream){
  (void)in_sizes; (void)n_in; (void)out_size;
  const float* x       = (const float*)d_in[0];
  const float* lins_w  = (const float*)d_in[1];
  // d_in[2] = lins_b: cancels inside BN, unused
  const float* skips_w = (const float*)d_in[3];
  const float* skips_b = (const float*)d_in[4];
  const float* bn_g    = (const float*)d_in[5];
  const float* bn_b    = (const float*)d_in[6];
  const float* lin9_w  = (const float*)d_in[7];
  // d_in[8] = lin9_b: cancels inside BN, unused
  const float* bn9_g   = (const float*)d_in[9];
  const float* bn9_b   = (const float*)d_in[10];
  const float* lin10_w = (const float*)d_in[11];
  const float* lin10_b = (const float*)d_in[12];
  float* out = (float*)d_out;

  float* stats = (float*)d_ws;
  hipMemsetAsync(stats, 0, STATS_BYTES, stream);

  void* args[13] = {
    (void*)&x, (void*)&stats, (void*)&lins_w, (void*)&bn_g, (void*)&bn_b,
    (void*)&skips_w, (void*)&skips_b, (void*)&lin9_w, (void*)&bn9_g,
    (void*)&bn9_b, (void*)&lin10_w, (void*)&lin10_b, (void*)&out
  };
  hipError_t e = hipLaunchCooperativeKernel((const void*)k_fused,
                                            dim3(BLK), dim3(THR),
                                            args, 0, stream);
  if(e != hipSuccess){
    // non-cooperative fallback: exact recompute-from-x chain (stats-only ws)
    for(int s=0; s<=8; ++s)
      k_fromx<<<BLK, THR, 0, stream>>>(x, stats, lins_w, bn_g, bn_b, skips_w,
                                       skips_b, lin9_w, bn9_g, bn9_b, lin10_w,
                                       lin10_b, out, s, 0);
    k_fromx<<<BLK, THR, 0, stream>>>(x, stats, lins_w, bn_g, bn_b, skips_w,
                                     skips_b, lin9_w, bn9_g, bn9_b, lin10_w,
                                     lin10_b, out, 8, 1);
  }
}